// Round 1
// baseline (475.680 us; speedup 1.0000x reference)
//
#include <hip/hip_runtime.h>

#define T2 128
#define MINV -100000.0f

// One block per batch element. 256 threads: thread owns to = tid&127,
// from-half h = tid>>7. E = exp(trans) held in registers (64 VGPR/thread).
// Scaled-prob domain: q'[to] = (sum_f E[to,f]*q[f]) * exp(feat[t,to]),
// sum-rescale every 8 steps, logacc accumulates log(scale).
__launch_bounds__(256, 1)
__global__ void crf_fwd(const float* __restrict__ feats,
                        const float* __restrict__ trans,
                        float* __restrict__ out, int S) {
  const int b   = blockIdx.x;
  const int tid = threadIdx.x;
  const int to  = tid & (T2 - 1);
  const int h   = tid >> 7;  // 0 or 1: which 64-wide from-chunk

  __shared__ __align__(16) float p_lds[T2];   // current q vector
  __shared__ float part[2][T2];               // per-half partial dots
  __shared__ float red[2];                    // cross-wave reduction

  // ---- init: E registers (exp of my 64 trans entries), end-transition weight
  float E[64];
  {
    const float* trow = trans + to * T2 + h * 64;
#pragma unroll
    for (int i = 0; i < 64; i += 4) {
      float4 tv = *reinterpret_cast<const float4*>(trow + i);
      E[i + 0] = expf(tv.x);
      E[i + 1] = expf(tv.y);
      E[i + 2] = expf(tv.z);
      E[i + 3] = expf(tv.w);
    }
  }
  const float eend = expf(trans[(T2 - 2) * T2 + to]);  // exp(trans[END, to])

  // q0 = one-hot at START (= last index). exp(MIN_VAL) underflows to 0 like ref.
  if (tid < T2) p_lds[tid] = (tid == T2 - 1) ? 1.0f : 0.0f;

  const float* fb = feats + (size_t)b * S * T2;
  float logacc = 0.0f;

  // feat prefetch for step 0
  float fn = (h == 0) ? fb[to] : 0.0f;
  float ef = __expf(fn);
  __syncthreads();

  for (int t = 0; t < S; ++t) {
    // prefetch feat row for step t+1 (coalesced, hidden under matvec)
    if (h == 0) {
      int tn = (t + 1 < S) ? (t + 1) : t;
      fn = fb[(size_t)tn * T2 + to];
    }

    // ---- matvec partial: dot(E_reg, q[h*64 .. h*64+63]) via LDS broadcast
    const float4* p4 = reinterpret_cast<const float4*>(&p_lds[h * 64]);
    float acc0 = 0.0f, acc1 = 0.0f;
#pragma unroll
    for (int i = 0; i < 16; ++i) {
      float4 pv = p4[i];
      acc0 = fmaf(E[4 * i + 0], pv.x, acc0);
      acc1 = fmaf(E[4 * i + 1], pv.y, acc1);
      acc0 = fmaf(E[4 * i + 2], pv.z, acc0);
      acc1 = fmaf(E[4 * i + 3], pv.w, acc1);
    }
    part[h][to] = acc0 + acc1;
    __syncthreads();  // A: partials visible

    float q = 0.0f;
    if (h == 0) q = (part[0][to] + part[1][to]) * ef;

    // ---- rescale every 8 steps (uniform branch: barrier inside is legal)
    if ((t & 7) == 7) {
      if (h == 0) {
        float s = q;
#pragma unroll
        for (int off = 32; off > 0; off >>= 1) s += __shfl_xor(s, off);
        if ((tid & 63) == 0) red[tid >> 6] = s;
      }
      __syncthreads();  // R
      if (h == 0) {
        float s = red[0] + red[1];
        q *= (1.0f / s);
        logacc += __logf(s);
      }
    }

    if (h == 0) p_lds[to] = q;
    __syncthreads();  // B: new q visible

    ef = __expf(fn);  // exp for step t+1 (computed off the critical LDS path)
  }

  // ---- epilogue: logZ = log(sum_to q[to] * exp(trans[END,to])) + logacc
  if (h == 0) {
    float w = p_lds[to] * eend;
#pragma unroll
    for (int off = 32; off > 0; off >>= 1) w += __shfl_xor(w, off);
    if ((tid & 63) == 0) red[tid >> 6] = w;
  }
  __syncthreads();
  if (tid == 0) out[b] = logf(red[0] + red[1]) + logacc;
}

extern "C" void kernel_launch(void* const* d_in, const int* in_sizes, int n_in,
                              void* d_out, int out_size, void* d_ws, size_t ws_size,
                              hipStream_t stream) {
  const float* feats = (const float*)d_in[0];
  const float* trans = (const float*)d_in[1];
  float* out = (float*)d_out;
  const int B = out_size;               // 256
  const int S = in_sizes[0] / (B * T2); // 1024
  crf_fwd<<<dim3(B), dim3(256), 0, stream>>>(feats, trans, out, S);
}